// Round 10
// baseline (1055.699 us; speedup 1.0000x reference)
//
#include <hip/hip_runtime.h>
#include <float.h>

// Problem constants
#define B   32
#define TE  1024
#define TD  64
#define DE  512
#define DD  512
#define U   512
#define K   512   // == DE == DD
#define NB  8     // blocks per batch (256-block coop launch: proven geometry)
#define RPB 128   // t-rows per block (slice size for outputs/slab)

#if __has_builtin(__builtin_amdgcn_exp2f)
#define EXP2F __builtin_amdgcn_exp2f
#else
#define EXP2F exp2f
#endif
#if __has_builtin(__builtin_amdgcn_rcpf)
#define RCPF __builtin_amdgcn_rcpf
#else
#define RCPF(x) (1.0f / (x))
#endif

#define TANH_C 2.8853900817779268f   // 2*log2(e)
#define L2E    1.4426950408889634f

typedef __attribute__((ext_vector_type(8))) short bf16x8;  // 8 bf16 = 4 VGPRs
typedef __attribute__((ext_vector_type(4))) float f32x4;

// Blocked bf16 operand layout (MFMA-native, wave-coalesced fragment loads):
//   element (m,k) of an [M][512] panel lives at
//   ((m>>4)*64 + (k>>3))*128 + (m&15)*8 + (k&7)

__device__ __forceinline__ float wave_reduce_sum(float v) {
    #pragma unroll
    for (int o = 32; o; o >>= 1) v += __shfl_xor(v, o, 64);
    return v;
}

// f32 -> bf16 RNE
__device__ __forceinline__ unsigned short f2bf(float f) {
    unsigned u = __float_as_uint(f);
    unsigned r = (u + 0x7fffu + ((u >> 16) & 1u)) >> 16;
    return (unsigned short)r;
}
__device__ __forceinline__ float bflo(unsigned x) { return __uint_as_float(x << 16); }
__device__ __forceinline__ float bfhi(unsigned x) { return __uint_as_float(x & 0xffff0000u); }
__device__ __forceinline__ void unpack8(uint4 q, float* f) {
    f[0] = bflo(q.x); f[1] = bfhi(q.x); f[2] = bflo(q.y); f[3] = bfhi(q.y);
    f[4] = bflo(q.z); f[5] = bfhi(q.z); f[6] = bflo(q.w); f[7] = bfhi(q.w);
}

// relaxed agent-scope accessors (tag exchange only)
__device__ __forceinline__ unsigned long long ld_agent64(const unsigned long long* p) {
    return __hip_atomic_load(p, __ATOMIC_RELAXED, __HIP_MEMORY_SCOPE_AGENT);
}
__device__ __forceinline__ void st_agent64(unsigned long long* p, unsigned long long v) {
    __hip_atomic_store(p, v, __ATOMIC_RELAXED, __HIP_MEMORY_SCOPE_AGENT);
}

// LDS-only barrier: no vmcnt drain (loop has no intra-kernel vmem reader)
#define LBAR() do { \
    asm volatile("s_waitcnt lgkmcnt(0)" ::: "memory"); \
    __builtin_amdgcn_s_barrier(); \
    __builtin_amdgcn_sched_barrier(0); \
} while (0)

// ---------------------------------------------------------------------------
// Fused prep, grid-strided over 3329 virtual blocks (identical to r9).
__global__ __launch_bounds__(256) void k_prep(
        const float* __restrict__ en_seq, unsigned short* __restrict__ en_bf,
        const float* __restrict__ de_seq, unsigned short* __restrict__ de_bf,
        float4* __restrict__ outp,
        const float* __restrict__ W_h, unsigned short* __restrict__ Wh_t,
        const float* __restrict__ W_s, unsigned short* __restrict__ Ws_t,
        unsigned long long* __restrict__ stats)
{
    __shared__ __align__(16) unsigned char sbuf[16640];
    const int tid = threadIdx.x;
    for (int vb = blockIdx.x; vb < 3329; vb += 2048) {
        if (vb < 2176) {                 // blocked bf16 cast (en / de)
            const float* src; unsigned short* dst; int rb;
            if (vb < 2048) { src = en_seq; dst = en_bf; rb = vb; }
            else           { src = de_seq; dst = de_bf; rb = vb - 2048; }
            unsigned short* tbl = (unsigned short*)sbuf;   // [16][520] padded
            const float4* s4 = (const float4*)(src + (size_t)rb * 8192);
            #pragma unroll
            for (int i = 0; i < 8; i++) {                  // coalesced read
                int idx = tid + i * 256;                   // float4 index
                float4 f = s4[idx];
                ushort4 r; r.x = f2bf(f.x); r.y = f2bf(f.y);
                r.z = f2bf(f.z); r.w = f2bf(f.w);
                *(ushort4*)&tbl[(idx >> 7) * 520 + (idx & 127) * 4] = r;
            }
            __syncthreads();
            uint4* d4 = (uint4*)(dst + (size_t)rb * 8192); // coalesced write
            #pragma unroll
            for (int i = 0; i < 4; i++) {
                int c = tid + i * 256;                     // 8-elem chunk id
                d4[c] = *(const uint4*)&tbl[(c & 15) * 520 + (c >> 4) * 8];
            }
            __syncthreads();
        } else if (vb < 3200) {          // de_seq passthrough -> out[:,:,0:DD]
            size_t i = (size_t)(vb - 2176) * 256 + tid;
            size_t r = i >> 7, c = i & 127;
            outp[r * 256 + c] = ((const float4*)de_seq)[i];
        } else if (vb < 3328) {          // W transpose+cast, BLOCKED dest
            int id = vb - 3200;
            const float* W = (id < 64) ? W_h : W_s;
            unsigned short* Wt = (id < 64) ? Wh_t : Ws_t;
            int bid = id & 63;
            const int bx = bid & 7, by = bid >> 3;
            const int lx = tid & 63, ly = tid >> 6;
            float* t = (float*)sbuf;     // [64][65]
            #pragma unroll
            for (int i = 0; i < 64; i += 4)
                t[(ly + i) * 65 + lx] =
                    W[(size_t)(by * 64 + ly + i) * 512 + bx * 64 + lx];
            __syncthreads();
            #pragma unroll
            for (int i = 0; i < 64; i += 4) {
                int n = bx * 64 + ly + i, k = by * 64 + lx;
                Wt[((size_t)(n >> 4) * 64 + (k >> 3)) * 128
                   + (n & 15) * 8 + (k & 7)] = f2bf(t[lx * 65 + ly + i]);
            }
            __syncthreads();
        } else {                         // stats init (512 u64)
            stats[tid] = 0ull;
            stats[tid + 256] = 0ull;
        }
    }
}

// ---------------------------------------------------------------------------
// Unified MFMA GEMM (identical to r9): blocked operands, 1 KB wave loads.
__global__ __launch_bounds__(256) void k_mfma(
        const unsigned short* __restrict__ Ae, const unsigned short* __restrict__ Be,
        unsigned short* __restrict__ Ce,
        const unsigned short* __restrict__ Ad, const unsigned short* __restrict__ Bd,
        unsigned short* __restrict__ Cd)
{
    const int tid = threadIdx.x;
    const int w = tid >> 6, lane = tid & 63;
    const int quad = lane >> 4, l16 = lane & 15;
    const short* A; const short* Bt; unsigned short* C; int mb;
    if (blockIdx.y < 256) {
        A = (const short*)Ae; Bt = (const short*)Be; C = Ce; mb = blockIdx.y * 128;
    } else {
        A = (const short*)Ad; Bt = (const short*)Bd; C = Cd; mb = (blockIdx.y - 256) * 128;
    }
    const int m0 = mb + (w >> 1) * 64;
    const int n0 = blockIdx.x * 128 + (w & 1) * 64;

    const short* Ab = A  + (size_t)(m0 >> 4) * 64 * 128 + l16 * 8;
    const short* Bb = Bt + (size_t)(n0 >> 4) * 64 * 128 + l16 * 8;

    f32x4 acc[4][4] = {};
    for (int ks = 0; ks < K; ks += 32) {
        const int kc = (ks >> 3) + quad;      // this lane's k-chunk
        bf16x8 af[4], bg[4];
        #pragma unroll
        for (int i = 0; i < 4; i++)
            af[i] = *(const bf16x8*)(Ab + ((size_t)i * 64 + kc) * 128);
        #pragma unroll
        for (int j = 0; j < 4; j++)
            bg[j] = *(const bf16x8*)(Bb + ((size_t)j * 64 + kc) * 128);
        #pragma unroll
        for (int i = 0; i < 4; i++)
            #pragma unroll
            for (int j = 0; j < 4; j++)
                acc[i][j] = __builtin_amdgcn_mfma_f32_16x16x32_bf16(
                    af[i], bg[j], acc[i][j], 0, 0, 0);
    }
    #pragma unroll
    for (int i = 0; i < 4; i++)
        #pragma unroll
        for (int j = 0; j < 4; j++)
            #pragma unroll
            for (int r = 0; r < 4; r++) {
                int m = m0 + i * 16 + quad * 4 + r;
                int n = n0 + j * 16 + l16;
                C[(size_t)m * U + n] = f2bf(acc[i][j][r]);
            }
}

// ---------------------------------------------------------------------------
// Persistent scan v8: 256 blocks x 1024 threads, cooperative.
// = r9 skeleton (single-poller + balanced dealing + fused phase5 + LDS-only
// barriers, proven 352us) + PART-A/PART-B PHASE1 SPLIT:
//   arg(s) = cov(s)*wcc + e*C + dfc(s),  cov(s) = cov(s-1) + aprev
//   base(s) := cov(s-1)*wcc + e*C + dfc(s)   [inv-independent!]
//   arg(s) = fma(aprev, wcc, base(s))
// base(s+1) (2 fma + bf16 unpack + LDS enc read per element, ~40% of phase1
// issue) is computed in the publish->poll window of step s, hiding the tag
// RTT that previously left 15 waves idle at B2. Per-lane state: 5 slots x
// 8 f32 = 40 VGPR, statically unrolled (slots >= 5 fall back to inline base
// computation -- never triggered at nact~512). Numerics: one fma
// re-association on arg (~1 ulp); all other paths identical.
__global__ __launch_bounds__(1024, 4) void k_scan(
        const unsigned short* __restrict__ enc_bf,
        const unsigned short* __restrict__ dec_bf,
        const unsigned short* en_bf,     // aliases pctx!
        const float* __restrict__ w_c,
        const float* __restrict__ v,
        const int* __restrict__ mask,
        unsigned long long* __restrict__ stats,  // [2][B][NB]
        float* pctx,                     // aliases en_bf! per-(b,g) slabs
        float* __restrict__ out)
{
    const int blk = blockIdx.x;
    const int b = blk & 31, g = blk >> 5;    // batch's 8 blocks share an XCD
    const int tid = threadIdx.x;
    const int w = tid >> 6, lane = tid & 63;
    const int u = lane * 8;

    __shared__ __align__(16) unsigned short s_enc[RPB * U];  // 128 KiB (by slot)
    __shared__ __align__(16) float s_p[RPB];  // unnormalized exp2(mu*L2E)/slot
    __shared__ float  s_cov[RPB];     // coverage per slot
    __shared__ short  s_rowid[RPB];   // slot -> batch row
    __shared__ unsigned long long s_bal[16];
    __shared__ float  s_wsum[16];
    __shared__ float  s_q[4][512];    // quarter ctx partials, 8 KiB
    __shared__ float  s_inv;

    const int* maskb = mask + b * TE;
    float* alphas = out + (size_t)B * TD * (DD + DE);
    float* covl   = alphas + (size_t)B * TD * TE;

    // lane-resident fragments: wcc = w_c*c (prescaled), vv, vsum (per-lane)
    float wcc[8], vv[8], vsuml;
    {
        float4 a0 = *(const float4*)&w_c[u];
        float4 a1 = *(const float4*)&w_c[u + 4];
        wcc[0]=a0.x*TANH_C; wcc[1]=a0.y*TANH_C; wcc[2]=a0.z*TANH_C; wcc[3]=a0.w*TANH_C;
        wcc[4]=a1.x*TANH_C; wcc[5]=a1.y*TANH_C; wcc[6]=a1.z*TANH_C; wcc[7]=a1.w*TANH_C;
        float4 b0 = *(const float4*)&v[u];
        float4 b1 = *(const float4*)&v[u + 4];
        vv[0]=b0.x; vv[1]=b0.y; vv[2]=b0.z; vv[3]=b0.w;
        vv[4]=b1.x; vv[5]=b1.y; vv[6]=b1.z; vv[7]=b1.w;
        vsuml = ((vv[0]+vv[1])+(vv[2]+vv[3])) + ((vv[4]+vv[5])+(vv[6]+vv[7]));
    }

    // ---- global active-row compaction (identical in all 8 blocks of b)
    int act = (maskb[tid] != 0);
    {
        unsigned long long bal = __ballot(act);
        if (lane == 0) s_bal[w] = bal;
        if (tid < RPB) { s_p[tid] = 0.f; s_cov[tid] = 0.f; s_rowid[tid] = 0; }
        __syncthreads();
    }
    int nact = 0, pre = 0;
    {
        #pragma unroll
        for (int ww = 0; ww < 16; ww++) {
            int c = __popcll(s_bal[ww]);
            if (ww < w) pre += c;
            nact += c;
        }
        pre += __popcll(s_bal[w] & ((1ull << lane) - 1));
        if (act && (pre & 7) == g) s_rowid[pre >> 3] = (short)tid;
    }
    const int Sblk = (nact + 7 - g) >> 3;    // assigned slots (<=128)

    // ---- zero alpha/covl for inactive rows of OWN slice, all steps (once)
    for (int t = tid; t < RPB * TD; t += 1024) {
        int rl = t & 127, s = t >> 7;
        if (maskb[g * RPB + rl] == 0) {
            size_t rowo = ((size_t)b * TD + s) * TE + g * RPB + rl;
            alphas[rowo] = 0.f;
            covl[rowo]   = 0.f;
        }
    }
    __syncthreads();   // s_rowid ready

    // ---- stage assigned rows' enc into LDS (slot-major), gather by rowid
    {
        const int slot = tid >> 3, part = tid & 7;   // 128 slots x 8 parts
        const uint4* src = (const uint4*)
            (enc_bf + ((size_t)b * TE + s_rowid[slot]) * U);
        uint4* dst = (uint4*)(s_enc + (size_t)slot * U);
        #pragma unroll
        for (int j = 0; j < 8; j++) dst[part + j * 8] = src[part + j * 8];
    }
    // ---- hoist assigned rows' en words (phase6 operands), by rowid
    //      en_bf is BLOCKED: word(rg,e2) = ((rg>>4)*64+(e2>>2))*64+(rg&15)*4+(e2&3)
    const int e2 = tid & 255, q4 = tid >> 8;   // 256 e-pairs x 4 quarters
    unsigned enreg[32];
    {
        const unsigned* enw = (const unsigned*)en_bf;
        #pragma unroll
        for (int r = 0; r < 32; r++) {
            int rg = b * TE + s_rowid[q4 * 32 + r];
            enreg[r] = enw[((size_t)(rg >> 4) * 64 + (e2 >> 2)) * 64
                           + (rg & 15) * 4 + (e2 & 3)];
        }
    }
    // private ctx slab: this (b,g)'s dead en_bf slice (64 steps x 512 f32)
    float* myctx = pctx + ((size_t)b * 1024 + g * RPB) * 256;

    __syncthreads();   // s_enc staged

    // ---- Part A/B split machinery -------------------------------------
    // MAKE_BASE: base_j = cov_prev*wcc_j + e_j*C + dfc_j  (inv-independent)
    #define MAKE_BASE(bb, ii) do { \
        const int i_ = (ii); \
        float covs_ = s_cov[i_]; \
        uint4 q_ = *(const uint4*)(s_enc + (size_t)i_ * U + u); \
        float e_[8]; unpack8(q_, e_); \
        _Pragma("unroll") \
        for (int j = 0; j < 8; j++) \
            (bb)[j] = fmaf(covs_, wcc[j], fmaf(e_[j], TANH_C, dfc[j])); \
    } while (0)

    // SLOT_B: finish phase1 for a slot using its precomputed base
    #define SLOT_B(bb, ii) do { \
        const int i_ = (ii); \
        float pold_ = s_p[i_]; \
        float covold_ = s_cov[i_]; \
        float aprev_ = pold_ * inv_prev; \
        float cov_ = covold_ + aprev_; \
        if (s > 0 && lane == 0) { \
            size_t rowo_ = ((size_t)b * TD + (s - 1)) * TE + s_rowid[i_]; \
            alphas[rowo_] = aprev_; \
            covl[rowo_]   = fminf(covold_, aprev_); \
        } \
        float acc2_ = 0.f; \
        _Pragma("unroll") \
        for (int j = 0; j < 8; j++) { \
            float arg_ = fmaf(aprev_, wcc[j], (bb)[j]); \
            acc2_ = fmaf(vv[j], RCPF(EXP2F(arg_) + 1.0f), acc2_); \
        } \
        float part_ = fmaf(acc2_, -2.0f, vsuml); \
        part_ = wave_reduce_sum(part_); \
        float pe_ = EXP2F(part_ * L2E); \
        if (lane == 0) { s_p[i_] = pe_; s_cov[i_] = cov_; } \
        local_esum += pe_; \
    } while (0)

    const int i0 = w, i1 = w + 16, i2 = w + 32, i3 = w + 48, i4 = w + 64;
    float base0[8], base1[8], base2[8], base3[8], base4[8];
    float dfc[8];

    // prologue: dec(0) fragment -> dfc(0); base(0) with cov=0
    uint4 qd = *(const uint4*)(dec_bf + ((size_t)b * TD) * U + u);
    unpack8(qd, dfc);
    #pragma unroll
    for (int j = 0; j < 8; j++) dfc[j] *= TANH_C;
    if (i0 < Sblk) MAKE_BASE(base0, i0);
    if (i1 < Sblk) MAKE_BASE(base1, i1);
    if (i2 < Sblk) MAKE_BASE(base2, i2);
    if (i3 < Sblk) MAKE_BASE(base3, i3);
    if (i4 < Sblk) MAKE_BASE(base4, i4);

    float inv_prev = 0.f;
    for (int s = 0; s < TD; s++) {
        // issue dec(s+1) prefetch; consumed in Part A (vmcnt wait lands there)
        {
            int sn = (s + 1 < TD) ? s + 1 : s;
            qd = *(const uint4*)(dec_bf + (((size_t)b * TD + sn) * U + u));
        }

        // ---- Part B: phase1(s) from precomputed base (+fused phase5(s-1))
        float local_esum = 0.f;
        if (i0 < Sblk) SLOT_B(base0, i0);
        if (i1 < Sblk) SLOT_B(base1, i1);
        if (i2 < Sblk) SLOT_B(base2, i2);
        if (i3 < Sblk) SLOT_B(base3, i3);
        if (i4 < Sblk) SLOT_B(base4, i4);
        for (int i = w + 80; i < Sblk; i += 16) {   // overflow slots (rare)
            float bt[8]; MAKE_BASE(bt, i); SLOT_B(bt, i);
        }
        if (lane == 0) s_wsum[w] = local_esum;

        LBAR();   // B1: s_p/s_cov/s_wsum visible (LDS-only; no vmcnt drain)

        // ---- publish (sum_g | tag s+1): wave 0 lane 0
        unsigned long long* sl = stats + ((size_t)(s & 1) * B + b) * NB;
        if (w == 0) {
            float x = (lane < 16) ? s_wsum[lane] : 0.f;
            x += __shfl_xor(x, 8, 64);
            x += __shfl_xor(x, 4, 64);
            x += __shfl_xor(x, 2, 64);
            x += __shfl_xor(x, 1, 64);            // lane0: sum of 16
            if (lane == 0) {
                unsigned long long pv =
                    ((unsigned long long)__float_as_uint(x) << 32) |
                    (unsigned)(s + 1);
                st_agent64(&sl[g], pv);
            }
        }

        // ---- Part A: dfc(s+1) + base(s+1)  (hidden under the tag RTT)
        if (s + 1 < TD) {
            unpack8(qd, dfc);
            #pragma unroll
            for (int j = 0; j < 8; j++) dfc[j] *= TANH_C;
            if (i0 < Sblk) MAKE_BASE(base0, i0);
            if (i1 < Sblk) MAKE_BASE(base1, i1);
            if (i2 < Sblk) MAKE_BASE(base2, i2);
            if (i3 < Sblk) MAKE_BASE(base3, i3);
            if (i4 < Sblk) MAKE_BASE(base4, i4);
        }

        // ---- phase 6: unnormalized ctx partial over own 32 slots -> s_q
        {
            const float4* pb = (const float4*)&s_p[q4 * 32];
            float a0 = 0.f, a1 = 0.f;
            #pragma unroll
            for (int k = 0; k < 8; k++) {
                float4 pp = pb[k];
                a0 = fmaf(pp.x, bflo(enreg[4*k]),   a0);
                a1 = fmaf(pp.x, bfhi(enreg[4*k]),   a1);
                a0 = fmaf(pp.y, bflo(enreg[4*k+1]), a0);
                a1 = fmaf(pp.y, bfhi(enreg[4*k+1]), a1);
                a0 = fmaf(pp.z, bflo(enreg[4*k+2]), a0);
                a1 = fmaf(pp.z, bfhi(enreg[4*k+2]), a1);
                a0 = fmaf(pp.w, bflo(enreg[4*k+3]), a0);
                a1 = fmaf(pp.w, bfhi(enreg[4*k+3]), a1);
            }
            s_q[q4][2 * e2]     = a0;
            s_q[q4][2 * e2 + 1] = a1;
        }

        // ---- SINGLE-POLLER: wave 0 polls 8 tags -> inv -> s_inv
        if (w == 0) {
            unsigned long long pv = 0;
            for (;;) {
                if (lane < NB) pv = ld_agent64(&sl[lane]);
                unsigned long long okm =
                    __ballot(lane < NB ? ((unsigned)pv == (unsigned)(s + 1)) : 1);
                if (~okm == 0ull) break;
                __builtin_amdgcn_s_sleep(1);
            }
            float tg = (lane < NB) ? __uint_as_float((unsigned)(pv >> 32)) : 0.f;
            tg = wave_reduce_sum(tg);
            if (lane == 0) s_inv = RCPF(tg);
        }

        LBAR();   // B2: s_q + s_inv visible (LDS-only)

        inv_prev = s_inv;

        // ---- ctx(s) reduce + normalized plain store to private slab
        if (tid < 512) {
            float ts = s_q[0][tid] + s_q[1][tid] + s_q[2][tid] + s_q[3][tid];
            myctx[(size_t)s * 512 + tid] = ts * inv_prev;
        }
    }
    #undef MAKE_BASE
    #undef SLOT_B

    // ---- epilogue: flush alpha/covl for s = TD-1
    for (int i = w; i < Sblk; i += 16) {
        if (lane == 0) {
            float aprev = s_p[i] * inv_prev;
            size_t rowo = ((size_t)b * TD + (TD - 1)) * TE + s_rowid[i];
            alphas[rowo] = aprev;
            covl[rowo]   = fminf(s_cov[i], aprev);
        }
    }
    // myctx/alphas/covl drained at kernel boundary; k_ctx reads after.
}

// ---------------------------------------------------------------------------
// ctx final reduce: out ctx = sum over the 8 per-block partials.
// pctx[b][g] slab at float offset (b*1024+g*128)*256, laid out [s][e].
// Grid-strided to 256 blocks.
__global__ __launch_bounds__(1024) void k_ctx(
        const float* __restrict__ pctx, float* __restrict__ out)
{
    for (int idx = blockIdx.x * 1024 + threadIdx.x; idx < 1048576;
         idx += 256 * 1024) {
        int b = idx >> 15, rem = idx & 32767;    // rem = s*512 + e
        const float* p = pctx + (size_t)b * 262144 + rem;
        float t = 0.f;
        #pragma unroll
        for (int g = 0; g < NB; g++) t += p[(size_t)g * 32768];
        int s = rem >> 9, e = rem & 511;
        out[((size_t)b * TD + s) * (DD + DE) + DD + e] = t;
    }
}

// ---------------------------------------------------------------------------
extern "C" void kernel_launch(void* const* d_in, const int* in_sizes, int n_in,
                              void* d_out, int out_size, void* d_ws, size_t ws_size,
                              hipStream_t stream) {
    const float* en_seq = (const float*)d_in[0];
    const float* de_seq = (const float*)d_in[1];
    const int*   mask   = (const int*)d_in[2];
    const float* W_h    = (const float*)d_in[3];
    const float* W_s    = (const float*)d_in[4];
    const float* w_c    = (const float*)d_in[5];
    const float* v      = (const float*)d_in[6];
    float* out = (float*)d_out;

    // workspace layout (~69 MiB, unchanged). en_bf doubles as the per-block
    // ctx-partial slab during k_scan (dead after the enreg hoist; per-batch
    // byte regions identical under the blocked layout).
    unsigned short* enc_bf = (unsigned short*)d_ws;        // B*TE*U  bf16 = 32 MiB
    unsigned short* en_bf  = enc_bf + (size_t)B * TE * U;  // B*TE*DE bf16 = 32 MiB (blocked)
    unsigned short* dec_bf = en_bf  + (size_t)B * TE * DE; // B*TD*U  bf16 = 2 MiB
    unsigned short* Wh_t   = dec_bf + (size_t)B * TD * U;  // 512*512 bf16 = 0.5 MiB (blocked)
    unsigned short* de_bf  = Wh_t   + (size_t)K * U;       // B*TD*DD bf16 = 2 MiB (blocked)
    unsigned short* Ws_t   = de_bf  + (size_t)B * TD * DD; // 0.5 MiB (blocked)
    unsigned long long* stats =
        (unsigned long long*)(Ws_t + (size_t)K * U);       // 512 u64
    float* pctx = (float*)en_bf;                           // alias

    k_prep<<<2048, 256, 0, stream>>>(en_seq, en_bf, de_seq, de_bf,
                                     (float4*)out, W_h, Wh_t, W_s, Ws_t, stats);
    k_mfma<<<dim3(4, 272), 256, 0, stream>>>(en_bf, Wh_t, enc_bf,
                                             de_bf, Ws_t, dec_bf);

    void* args[] = { (void*)&enc_bf, (void*)&dec_bf, (void*)&en_bf,
                     (void*)&w_c, (void*)&v, (void*)&mask,
                     (void*)&stats, (void*)&pctx, (void*)&out };
    hipLaunchCooperativeKernel((const void*)k_scan, dim3(256), dim3(1024),
                               args, 0, stream);

    k_ctx<<<256, 1024, 0, stream>>>(pctx, out);
}

// Round 12
// 529.132 us; speedup vs baseline: 1.9952x; 1.9952x over previous
//
#include <hip/hip_runtime.h>
#include <float.h>

// Problem constants
#define B   32
#define TE  1024
#define TD  64
#define DE  512
#define DD  512
#define U   512
#define K   512   // == DE == DD
#define NB  8     // blocks per batch (256-block coop launch: proven geometry)
#define RPB 128   // t-rows per block (slice size for outputs/slab)

#if __has_builtin(__builtin_amdgcn_exp2f)
#define EXP2F __builtin_amdgcn_exp2f
#else
#define EXP2F exp2f
#endif
#if __has_builtin(__builtin_amdgcn_rcpf)
#define RCPF __builtin_amdgcn_rcpf
#else
#define RCPF(x) (1.0f / (x))
#endif

#define TANH_C 2.8853900817779268f   // 2*log2(e)
#define L2E    1.4426950408889634f

typedef __attribute__((ext_vector_type(8))) short bf16x8;  // 8 bf16 = 4 VGPRs
typedef __attribute__((ext_vector_type(4))) float f32x4;

// Blocked bf16 operand layout (MFMA-native, wave-coalesced fragment loads):
//   element (m,k) of an [M][512] panel lives at
//   ((m>>4)*64 + (k>>3))*128 + (m&15)*8 + (k&7)

__device__ __forceinline__ float wave_reduce_sum(float v) {
    #pragma unroll
    for (int o = 32; o; o >>= 1) v += __shfl_xor(v, o, 64);
    return v;
}

// f32 -> bf16 RNE
__device__ __forceinline__ unsigned short f2bf(float f) {
    unsigned u = __float_as_uint(f);
    unsigned r = (u + 0x7fffu + ((u >> 16) & 1u)) >> 16;
    return (unsigned short)r;
}
__device__ __forceinline__ float bflo(unsigned x) { return __uint_as_float(x << 16); }
__device__ __forceinline__ float bfhi(unsigned x) { return __uint_as_float(x & 0xffff0000u); }
__device__ __forceinline__ void unpack8(uint4 q, float* f) {
    f[0] = bflo(q.x); f[1] = bfhi(q.x); f[2] = bflo(q.y); f[3] = bfhi(q.y);
    f[4] = bflo(q.z); f[5] = bfhi(q.z); f[6] = bflo(q.w); f[7] = bfhi(q.w);
}

// relaxed agent-scope accessors (tag exchange only)
__device__ __forceinline__ unsigned long long ld_agent64(const unsigned long long* p) {
    return __hip_atomic_load(p, __ATOMIC_RELAXED, __HIP_MEMORY_SCOPE_AGENT);
}
__device__ __forceinline__ void st_agent64(unsigned long long* p, unsigned long long v) {
    __hip_atomic_store(p, v, __ATOMIC_RELAXED, __HIP_MEMORY_SCOPE_AGENT);
}

// LDS-only barrier: no vmcnt drain (loop has no intra-kernel vmem reader)
#define LBAR() do { \
    asm volatile("s_waitcnt lgkmcnt(0)" ::: "memory"); \
    __builtin_amdgcn_s_barrier(); \
    __builtin_amdgcn_sched_barrier(0); \
} while (0)

// ---------------------------------------------------------------------------
// Fused prep, grid-strided over 3329 virtual blocks (identical to r9).
__global__ __launch_bounds__(256) void k_prep(
        const float* __restrict__ en_seq, unsigned short* __restrict__ en_bf,
        const float* __restrict__ de_seq, unsigned short* __restrict__ de_bf,
        float4* __restrict__ outp,
        const float* __restrict__ W_h, unsigned short* __restrict__ Wh_t,
        const float* __restrict__ W_s, unsigned short* __restrict__ Ws_t,
        unsigned long long* __restrict__ stats)
{
    __shared__ __align__(16) unsigned char sbuf[16640];
    const int tid = threadIdx.x;
    for (int vb = blockIdx.x; vb < 3329; vb += 2048) {
        if (vb < 2176) {                 // blocked bf16 cast (en / de)
            const float* src; unsigned short* dst; int rb;
            if (vb < 2048) { src = en_seq; dst = en_bf; rb = vb; }
            else           { src = de_seq; dst = de_bf; rb = vb - 2048; }
            unsigned short* tbl = (unsigned short*)sbuf;   // [16][520] padded
            const float4* s4 = (const float4*)(src + (size_t)rb * 8192);
            #pragma unroll
            for (int i = 0; i < 8; i++) {                  // coalesced read
                int idx = tid + i * 256;                   // float4 index
                float4 f = s4[idx];
                ushort4 r; r.x = f2bf(f.x); r.y = f2bf(f.y);
                r.z = f2bf(f.z); r.w = f2bf(f.w);
                *(ushort4*)&tbl[(idx >> 7) * 520 + (idx & 127) * 4] = r;
            }
            __syncthreads();
            uint4* d4 = (uint4*)(dst + (size_t)rb * 8192); // coalesced write
            #pragma unroll
            for (int i = 0; i < 4; i++) {
                int c = tid + i * 256;                     // 8-elem chunk id
                d4[c] = *(const uint4*)&tbl[(c & 15) * 520 + (c >> 4) * 8];
            }
            __syncthreads();
        } else if (vb < 3200) {          // de_seq passthrough -> out[:,:,0:DD]
            size_t i = (size_t)(vb - 2176) * 256 + tid;
            size_t r = i >> 7, c = i & 127;
            outp[r * 256 + c] = ((const float4*)de_seq)[i];
        } else if (vb < 3328) {          // W transpose+cast, BLOCKED dest
            int id = vb - 3200;
            const float* W = (id < 64) ? W_h : W_s;
            unsigned short* Wt = (id < 64) ? Wh_t : Ws_t;
            int bid = id & 63;
            const int bx = bid & 7, by = bid >> 3;
            const int lx = tid & 63, ly = tid >> 6;
            float* t = (float*)sbuf;     // [64][65]
            #pragma unroll
            for (int i = 0; i < 64; i += 4)
                t[(ly + i) * 65 + lx] =
                    W[(size_t)(by * 64 + ly + i) * 512 + bx * 64 + lx];
            __syncthreads();
            #pragma unroll
            for (int i = 0; i < 64; i += 4) {
                int n = bx * 64 + ly + i, k = by * 64 + lx;
                Wt[((size_t)(n >> 4) * 64 + (k >> 3)) * 128
                   + (n & 15) * 8 + (k & 7)] = f2bf(t[lx * 65 + ly + i]);
            }
            __syncthreads();
        } else {                         // stats init (512 u64)
            stats[tid] = 0ull;
            stats[tid + 256] = 0ull;
        }
    }
}

// ---------------------------------------------------------------------------
// Unified MFMA GEMM (identical to r9): blocked operands, 1 KB wave loads.
__global__ __launch_bounds__(256) void k_mfma(
        const unsigned short* __restrict__ Ae, const unsigned short* __restrict__ Be,
        unsigned short* __restrict__ Ce,
        const unsigned short* __restrict__ Ad, const unsigned short* __restrict__ Bd,
        unsigned short* __restrict__ Cd)
{
    const int tid = threadIdx.x;
    const int w = tid >> 6, lane = tid & 63;
    const int quad = lane >> 4, l16 = lane & 15;
    const short* A; const short* Bt; unsigned short* C; int mb;
    if (blockIdx.y < 256) {
        A = (const short*)Ae; Bt = (const short*)Be; C = Ce; mb = blockIdx.y * 128;
    } else {
        A = (const short*)Ad; Bt = (const short*)Bd; C = Cd; mb = (blockIdx.y - 256) * 128;
    }
    const int m0 = mb + (w >> 1) * 64;
    const int n0 = blockIdx.x * 128 + (w & 1) * 64;

    const short* Ab = A  + (size_t)(m0 >> 4) * 64 * 128 + l16 * 8;
    const short* Bb = Bt + (size_t)(n0 >> 4) * 64 * 128 + l16 * 8;

    f32x4 acc[4][4] = {};
    for (int ks = 0; ks < K; ks += 32) {
        const int kc = (ks >> 3) + quad;      // this lane's k-chunk
        bf16x8 af[4], bg[4];
        #pragma unroll
        for (int i = 0; i < 4; i++)
            af[i] = *(const bf16x8*)(Ab + ((size_t)i * 64 + kc) * 128);
        #pragma unroll
        for (int j = 0; j < 4; j++)
            bg[j] = *(const bf16x8*)(Bb + ((size_t)j * 64 + kc) * 128);
        #pragma unroll
        for (int i = 0; i < 4; i++)
            #pragma unroll
            for (int j = 0; j < 4; j++)
                acc[i][j] = __builtin_amdgcn_mfma_f32_16x16x32_bf16(
                    af[i], bg[j], acc[i][j], 0, 0, 0);
    }
    #pragma unroll
    for (int i = 0; i < 4; i++)
        #pragma unroll
        for (int j = 0; j < 4; j++)
            #pragma unroll
            for (int r = 0; r < 4; r++) {
                int m = m0 + i * 16 + quad * 4 + r;
                int n = n0 + j * 16 + l16;
                C[(size_t)m * U + n] = f2bf(acc[i][j][r]);
            }
}

// ---------------------------------------------------------------------------
// Persistent scan v10: 256 blocks x 1024 threads, cooperative.
// = r9 (proven 352us) with ONE change: PAIRED RECIPROCALS in phase1.
//   vv1/(E1+1) + vv2/(E2+1) = (vv1*b + vv2*a) * rcp(a*b),  a=E1+1, b=E2+1
// Exact algebra (no approximation): per slot, transcendentals 17 -> 13
// (8 exp2 + 4 rcp + 1 slot-exp2), VALU +8. If the trans unit and main VALU
// overlap across waves (m114), phase1's trans-bound cost drops ~24%.
// Overflow-safe: a*b <= 2^121 needs arg <= 60 = 13 sigma -- unreachable.
// Registers unchanged (~64, no spill). Sync skeleton byte-identical to r9.
__global__ __launch_bounds__(1024, 4) void k_scan(
        const unsigned short* __restrict__ enc_bf,
        const unsigned short* __restrict__ dec_bf,
        const unsigned short* en_bf,     // aliases pctx!
        const float* __restrict__ w_c,
        const float* __restrict__ v,
        const int* __restrict__ mask,
        unsigned long long* __restrict__ stats,  // [2][B][NB]
        float* pctx,                     // aliases en_bf! per-(b,g) slabs
        float* __restrict__ out)
{
    const int blk = blockIdx.x;
    const int b = blk & 31, g = blk >> 5;    // batch's 8 blocks share an XCD
    const int tid = threadIdx.x;
    const int w = tid >> 6, lane = tid & 63;
    const int u = lane * 8;

    __shared__ __align__(16) unsigned short s_enc[RPB * U];  // 128 KiB (by slot)
    __shared__ __align__(16) float s_p[RPB];  // unnormalized exp2(mu*L2E)/slot
    __shared__ float  s_cov[RPB];     // coverage per slot
    __shared__ short  s_rowid[RPB];   // slot -> batch row
    __shared__ unsigned long long s_bal[16];
    __shared__ float  s_wsum[16];
    __shared__ float  s_q[4][512];    // quarter ctx partials, 8 KiB
    __shared__ float  s_inv;

    const int* maskb = mask + b * TE;
    float* alphas = out + (size_t)B * TD * (DD + DE);
    float* covl   = alphas + (size_t)B * TD * TE;

    // lane-resident fragments: wcc = w_c*c (prescaled), vv, vsum (per-lane)
    float wcc[8], vv[8], vsuml;
    {
        float4 a0 = *(const float4*)&w_c[u];
        float4 a1 = *(const float4*)&w_c[u + 4];
        wcc[0]=a0.x*TANH_C; wcc[1]=a0.y*TANH_C; wcc[2]=a0.z*TANH_C; wcc[3]=a0.w*TANH_C;
        wcc[4]=a1.x*TANH_C; wcc[5]=a1.y*TANH_C; wcc[6]=a1.z*TANH_C; wcc[7]=a1.w*TANH_C;
        float4 b0 = *(const float4*)&v[u];
        float4 b1 = *(const float4*)&v[u + 4];
        vv[0]=b0.x; vv[1]=b0.y; vv[2]=b0.z; vv[3]=b0.w;
        vv[4]=b1.x; vv[5]=b1.y; vv[6]=b1.z; vv[7]=b1.w;
        vsuml = ((vv[0]+vv[1])+(vv[2]+vv[3])) + ((vv[4]+vv[5])+(vv[6]+vv[7]));
    }

    // ---- global active-row compaction (identical in all 8 blocks of b)
    int act = (maskb[tid] != 0);
    {
        unsigned long long bal = __ballot(act);
        if (lane == 0) s_bal[w] = bal;
        if (tid < RPB) { s_p[tid] = 0.f; s_cov[tid] = 0.f; s_rowid[tid] = 0; }
        __syncthreads();
    }
    int nact = 0, pre = 0;
    {
        #pragma unroll
        for (int ww = 0; ww < 16; ww++) {
            int c = __popcll(s_bal[ww]);
            if (ww < w) pre += c;
            nact += c;
        }
        pre += __popcll(s_bal[w] & ((1ull << lane) - 1));
        if (act && (pre & 7) == g) s_rowid[pre >> 3] = (short)tid;
    }
    const int Sblk = (nact + 7 - g) >> 3;    // assigned slots (<=128)

    // ---- zero alpha/covl for inactive rows of OWN slice, all steps (once)
    for (int t = tid; t < RPB * TD; t += 1024) {
        int rl = t & 127, s = t >> 7;
        if (maskb[g * RPB + rl] == 0) {
            size_t rowo = ((size_t)b * TD + s) * TE + g * RPB + rl;
            alphas[rowo] = 0.f;
            covl[rowo]   = 0.f;
        }
    }
    __syncthreads();   // s_rowid ready

    // ---- stage assigned rows' enc into LDS (slot-major), gather by rowid
    {
        const int slot = tid >> 3, part = tid & 7;   // 128 slots x 8 parts
        const uint4* src = (const uint4*)
            (enc_bf + ((size_t)b * TE + s_rowid[slot]) * U);
        uint4* dst = (uint4*)(s_enc + (size_t)slot * U);
        #pragma unroll
        for (int j = 0; j < 8; j++) dst[part + j * 8] = src[part + j * 8];
    }
    // ---- hoist assigned rows' en words (phase6 operands), by rowid
    //      en_bf is BLOCKED: word(rg,e2) = ((rg>>4)*64+(e2>>2))*64+(rg&15)*4+(e2&3)
    const int e2 = tid & 255, q4 = tid >> 8;   // 256 e-pairs x 4 quarters
    unsigned enreg[32];
    {
        const unsigned* enw = (const unsigned*)en_bf;
        #pragma unroll
        for (int r = 0; r < 32; r++) {
            int rg = b * TE + s_rowid[q4 * 32 + r];
            enreg[r] = enw[((size_t)(rg >> 4) * 64 + (e2 >> 2)) * 64
                           + (rg & 15) * 4 + (e2 & 3)];
        }
    }
    // private ctx slab: this (b,g)'s dead en_bf slice (64 steps x 512 f32)
    float* myctx = pctx + ((size_t)b * 1024 + g * RPB) * 256;

    __syncthreads();   // s_enc staged

    // pipelined dec fragment
    uint4 qd = *(const uint4*)(dec_bf + ((size_t)b * TD) * U + u);

    float inv_prev = 0.f;
    for (int s = 0; s < TD; s++) {
        // dfc = df * c (prescaled for the folded tanh argument)
        float dfc[8];
        unpack8(qd, dfc);
        #pragma unroll
        for (int j = 0; j < 8; j++) dfc[j] *= TANH_C;

        // ---- phase 1 (+fused phase 5 of step s-1) over own slots
        float local_esum = 0.f;
        for (int i = w; i < Sblk; i += 16) {
            float pold   = s_p[i];
            float covold = s_cov[i];
            float aprev  = pold * inv_prev;
            float cov    = covold + aprev;        // cov(s)
            if (s > 0 && lane == 0) {
                size_t rowo = ((size_t)b * TD + (s - 1)) * TE + s_rowid[i];
                alphas[rowo] = aprev;
                covl[rowo]   = fminf(covold, aprev);
            }
            uint4 q = *(const uint4*)(s_enc + (size_t)i * U + u);
            float e[8]; unpack8(q, e);
            float acc2 = 0.f;
            #pragma unroll
            for (int p = 0; p < 4; p++) {
                float arg0 = fmaf(cov, wcc[2*p],
                                  fmaf(e[2*p],   TANH_C, dfc[2*p]));
                float arg1 = fmaf(cov, wcc[2*p+1],
                                  fmaf(e[2*p+1], TANH_C, dfc[2*p+1]));
                float pa = EXP2F(arg0) + 1.0f;
                float pb = EXP2F(arg1) + 1.0f;
                float num = fmaf(vv[2*p], pb, vv[2*p+1] * pa);
                acc2 = fmaf(num, RCPF(pa * pb), acc2);
            }
            // per-lane mu partial = vsum_l - 2*acc2_l (original cancellation)
            float part = fmaf(acc2, -2.0f, vsuml);
            part = wave_reduce_sum(part);         // = mu (wave-uniform)
            float pe = EXP2F(part * L2E);
            if (lane == 0) { s_p[i] = pe; s_cov[i] = cov; }
            local_esum += pe;
        }
        if (lane == 0) s_wsum[w] = local_esum;

        LBAR();   // B1: s_p/s_cov/s_wsum visible (LDS-only; no vmcnt drain)

        // ---- publish (sum_g | tag s+1): wave 0 lane 0
        unsigned long long* sl = stats + ((size_t)(s & 1) * B + b) * NB;
        if (w == 0) {
            float x = (lane < 16) ? s_wsum[lane] : 0.f;
            x += __shfl_xor(x, 8, 64);
            x += __shfl_xor(x, 4, 64);
            x += __shfl_xor(x, 2, 64);
            x += __shfl_xor(x, 1, 64);            // lane0: sum of 16
            if (lane == 0) {
                unsigned long long pv =
                    ((unsigned long long)__float_as_uint(x) << 32) |
                    (unsigned)(s + 1);
                st_agent64(&sl[g], pv);
            }
        }

        // ---- prefetch next dec fragment (hides under phase6 + poll)
        {
            int sn = (s + 1 < TD) ? s + 1 : s;
            qd = *(const uint4*)(dec_bf + (((size_t)b * TD + sn) * U + u));
        }

        // ---- phase 6: unnormalized ctx partial over own 32 slots -> s_q
        //      (s_p read as 8x float4: 4x fewer LDS instructions)
        {
            const float4* pb4 = (const float4*)&s_p[q4 * 32];
            float a0 = 0.f, a1 = 0.f;
            #pragma unroll
            for (int k = 0; k < 8; k++) {
                float4 pp = pb4[k];
                a0 = fmaf(pp.x, bflo(enreg[4*k]),   a0);
                a1 = fmaf(pp.x, bfhi(enreg[4*k]),   a1);
                a0 = fmaf(pp.y, bflo(enreg[4*k+1]), a0);
                a1 = fmaf(pp.y, bfhi(enreg[4*k+1]), a1);
                a0 = fmaf(pp.z, bflo(enreg[4*k+2]), a0);
                a1 = fmaf(pp.z, bfhi(enreg[4*k+2]), a1);
                a0 = fmaf(pp.w, bflo(enreg[4*k+3]), a0);
                a1 = fmaf(pp.w, bfhi(enreg[4*k+3]), a1);
            }
            s_q[q4][2 * e2]     = a0;
            s_q[q4][2 * e2 + 1] = a1;
        }

        // ---- SINGLE-POLLER: wave 0 polls 8 tags -> inv -> s_inv
        if (w == 0) {
            unsigned long long pv = 0;
            for (;;) {
                if (lane < NB) pv = ld_agent64(&sl[lane]);
                unsigned long long okm =
                    __ballot(lane < NB ? ((unsigned)pv == (unsigned)(s + 1)) : 1);
                if (~okm == 0ull) break;
                __builtin_amdgcn_s_sleep(1);
            }
            float tg = (lane < NB) ? __uint_as_float((unsigned)(pv >> 32)) : 0.f;
            tg = wave_reduce_sum(tg);
            if (lane == 0) s_inv = RCPF(tg);
        }

        LBAR();   // B2: s_q + s_inv visible (LDS-only)

        inv_prev = s_inv;

        // ---- ctx(s) reduce + normalized plain store to private slab
        if (tid < 512) {
            float ts = s_q[0][tid] + s_q[1][tid] + s_q[2][tid] + s_q[3][tid];
            myctx[(size_t)s * 512 + tid] = ts * inv_prev;
        }
    }

    // ---- epilogue: flush alpha/covl for s = TD-1
    for (int i = w; i < Sblk; i += 16) {
        if (lane == 0) {
            float aprev = s_p[i] * inv_prev;
            size_t rowo = ((size_t)b * TD + (TD - 1)) * TE + s_rowid[i];
            alphas[rowo] = aprev;
            covl[rowo]   = fminf(s_cov[i], aprev);
        }
    }
    // myctx/alphas/covl drained at kernel boundary; k_ctx reads after.
}

// ---------------------------------------------------------------------------
// ctx final reduce: out ctx = sum over the 8 per-block partials.
// pctx[b][g] slab at float offset (b*1024+g*128)*256, laid out [s][e].
// Grid-strided to 256 blocks.
__global__ __launch_bounds__(1024) void k_ctx(
        const float* __restrict__ pctx, float* __restrict__ out)
{
    for (int idx = blockIdx.x * 1024 + threadIdx.x; idx < 1048576;
         idx += 256 * 1024) {
        int b = idx >> 15, rem = idx & 32767;    // rem = s*512 + e
        const float* p = pctx + (size_t)b * 262144 + rem;
        float t = 0.f;
        #pragma unroll
        for (int g = 0; g < NB; g++) t += p[(size_t)g * 32768];
        int s = rem >> 9, e = rem & 511;
        out[((size_t)b * TD + s) * (DD + DE) + DD + e] = t;
    }
}

// ---------------------------------------------------------------------------
extern "C" void kernel_launch(void* const* d_in, const int* in_sizes, int n_in,
                              void* d_out, int out_size, void* d_ws, size_t ws_size,
                              hipStream_t stream) {
    const float* en_seq = (const float*)d_in[0];
    const float* de_seq = (const float*)d_in[1];
    const int*   mask   = (const int*)d_in[2];
    const float* W_h    = (const float*)d_in[3];
    const float* W_s    = (const float*)d_in[4];
    const float* w_c    = (const float*)d_in[5];
    const float* v      = (const float*)d_in[6];
    float* out = (float*)d_out;

    // workspace layout (~69 MiB, unchanged). en_bf doubles as the per-block
    // ctx-partial slab during k_scan (dead after the enreg hoist; per-batch
    // byte regions identical under the blocked layout).
    unsigned short* enc_bf = (unsigned short*)d_ws;        // B*TE*U  bf16 = 32 MiB
    unsigned short* en_bf  = enc_bf + (size_t)B * TE * U;  // B*TE*DE bf16 = 32 MiB (blocked)
    unsigned short* dec_bf = en_bf  + (size_t)B * TE * DE; // B*TD*U  bf16 = 2 MiB
    unsigned short* Wh_t   = dec_bf + (size_t)B * TD * U;  // 512*512 bf16 = 0.5 MiB (blocked)
    unsigned short* de_bf  = Wh_t   + (size_t)K * U;       // B*TD*DD bf16 = 2 MiB (blocked)
    unsigned short* Ws_t   = de_bf  + (size_t)B * TD * DD; // 0.5 MiB (blocked)
    unsigned long long* stats =
        (unsigned long long*)(Ws_t + (size_t)K * U);       // 512 u64
    float* pctx = (float*)en_bf;                           // alias

    k_prep<<<2048, 256, 0, stream>>>(en_seq, en_bf, de_seq, de_bf,
                                     (float4*)out, W_h, Wh_t, W_s, Ws_t, stats);
    k_mfma<<<dim3(4, 272), 256, 0, stream>>>(en_bf, Wh_t, enc_bf,
                                             de_bf, Ws_t, dec_bf);

    void* args[] = { (void*)&enc_bf, (void*)&dec_bf, (void*)&en_bf,
                     (void*)&w_c, (void*)&v, (void*)&mask,
                     (void*)&stats, (void*)&pctx, (void*)&out };
    hipLaunchCooperativeKernel((const void*)k_scan, dim3(256), dim3(1024),
                               args, 0, stream);

    k_ctx<<<256, 1024, 0, stream>>>(pctx, out);
}

// Round 13
// 524.533 us; speedup vs baseline: 2.0126x; 1.0088x over previous
//
#include <hip/hip_runtime.h>
#include <float.h>

// Problem constants
#define B   32
#define TE  1024
#define TD  64
#define DE  512
#define DD  512
#define U   512
#define K   512   // == DE == DD
#define NB  8     // blocks per batch (256-block coop launch: proven geometry)
#define RPB 128   // t-rows per block (slice size for outputs/slab)

#if __has_builtin(__builtin_amdgcn_exp2f)
#define EXP2F __builtin_amdgcn_exp2f
#else
#define EXP2F exp2f
#endif
#if __has_builtin(__builtin_amdgcn_rcpf)
#define RCPF __builtin_amdgcn_rcpf
#else
#define RCPF(x) (1.0f / (x))
#endif

#define TANH_C 2.8853900817779268f   // 2*log2(e)
#define L2E    1.4426950408889634f

typedef __attribute__((ext_vector_type(8))) short bf16x8;  // 8 bf16 = 4 VGPRs
typedef __attribute__((ext_vector_type(4))) float f32x4;

// Blocked bf16 operand layout (MFMA-native, wave-coalesced fragment loads):
//   element (m,k) of an [M][512] panel lives at
//   ((m>>4)*64 + (k>>3))*128 + (m&15)*8 + (k&7)

__device__ __forceinline__ float wave_reduce_sum(float v) {
    #pragma unroll
    for (int o = 32; o; o >>= 1) v += __shfl_xor(v, o, 64);
    return v;
}

// f32 -> bf16 RNE
__device__ __forceinline__ unsigned short f2bf(float f) {
    unsigned u = __float_as_uint(f);
    unsigned r = (u + 0x7fffu + ((u >> 16) & 1u)) >> 16;
    return (unsigned short)r;
}
__device__ __forceinline__ float bflo(unsigned x) { return __uint_as_float(x << 16); }
__device__ __forceinline__ float bfhi(unsigned x) { return __uint_as_float(x & 0xffff0000u); }
__device__ __forceinline__ void unpack8(uint4 q, float* f) {
    f[0] = bflo(q.x); f[1] = bfhi(q.x); f[2] = bflo(q.y); f[3] = bfhi(q.y);
    f[4] = bflo(q.z); f[5] = bfhi(q.z); f[6] = bflo(q.w); f[7] = bfhi(q.w);
}

// relaxed agent-scope accessors (tag exchange + ctx slab)
__device__ __forceinline__ float ld_agent(const float* p) {
    return __hip_atomic_load(p, __ATOMIC_RELAXED, __HIP_MEMORY_SCOPE_AGENT);
}
__device__ __forceinline__ void st_agent(float* p, float v) {
    __hip_atomic_store(p, v, __ATOMIC_RELAXED, __HIP_MEMORY_SCOPE_AGENT);
}
__device__ __forceinline__ unsigned long long ld_agent64(const unsigned long long* p) {
    return __hip_atomic_load(p, __ATOMIC_RELAXED, __HIP_MEMORY_SCOPE_AGENT);
}
__device__ __forceinline__ void st_agent64(unsigned long long* p, unsigned long long v) {
    __hip_atomic_store(p, v, __ATOMIC_RELAXED, __HIP_MEMORY_SCOPE_AGENT);
}

// LDS-only barrier: no vmcnt drain (loop has no intra-kernel vmem reader)
#define LBAR() do { \
    asm volatile("s_waitcnt lgkmcnt(0)" ::: "memory"); \
    __builtin_amdgcn_s_barrier(); \
    __builtin_amdgcn_sched_barrier(0); \
} while (0)

// ---------------------------------------------------------------------------
// Fused prep, grid-strided over 3329 virtual blocks (identical to r9).
__global__ __launch_bounds__(256) void k_prep(
        const float* __restrict__ en_seq, unsigned short* __restrict__ en_bf,
        const float* __restrict__ de_seq, unsigned short* __restrict__ de_bf,
        float4* __restrict__ outp,
        const float* __restrict__ W_h, unsigned short* __restrict__ Wh_t,
        const float* __restrict__ W_s, unsigned short* __restrict__ Ws_t,
        unsigned long long* __restrict__ stats)
{
    __shared__ __align__(16) unsigned char sbuf[16640];
    const int tid = threadIdx.x;
    for (int vb = blockIdx.x; vb < 3329; vb += 2048) {
        if (vb < 2176) {                 // blocked bf16 cast (en / de)
            const float* src; unsigned short* dst; int rb;
            if (vb < 2048) { src = en_seq; dst = en_bf; rb = vb; }
            else           { src = de_seq; dst = de_bf; rb = vb - 2048; }
            unsigned short* tbl = (unsigned short*)sbuf;   // [16][520] padded
            const float4* s4 = (const float4*)(src + (size_t)rb * 8192);
            #pragma unroll
            for (int i = 0; i < 8; i++) {                  // coalesced read
                int idx = tid + i * 256;                   // float4 index
                float4 f = s4[idx];
                ushort4 r; r.x = f2bf(f.x); r.y = f2bf(f.y);
                r.z = f2bf(f.z); r.w = f2bf(f.w);
                *(ushort4*)&tbl[(idx >> 7) * 520 + (idx & 127) * 4] = r;
            }
            __syncthreads();
            uint4* d4 = (uint4*)(dst + (size_t)rb * 8192); // coalesced write
            #pragma unroll
            for (int i = 0; i < 4; i++) {
                int c = tid + i * 256;                     // 8-elem chunk id
                d4[c] = *(const uint4*)&tbl[(c & 15) * 520 + (c >> 4) * 8];
            }
            __syncthreads();
        } else if (vb < 3200) {          // de_seq passthrough -> out[:,:,0:DD]
            size_t i = (size_t)(vb - 2176) * 256 + tid;
            size_t r = i >> 7, c = i & 127;
            outp[r * 256 + c] = ((const float4*)de_seq)[i];
        } else if (vb < 3328) {          // W transpose+cast, BLOCKED dest
            int id = vb - 3200;
            const float* W = (id < 64) ? W_h : W_s;
            unsigned short* Wt = (id < 64) ? Wh_t : Ws_t;
            int bid = id & 63;
            const int bx = bid & 7, by = bid >> 3;
            const int lx = tid & 63, ly = tid >> 6;
            float* t = (float*)sbuf;     // [64][65]
            #pragma unroll
            for (int i = 0; i < 64; i += 4)
                t[(ly + i) * 65 + lx] =
                    W[(size_t)(by * 64 + ly + i) * 512 + bx * 64 + lx];
            __syncthreads();
            #pragma unroll
            for (int i = 0; i < 64; i += 4) {
                int n = bx * 64 + ly + i, k = by * 64 + lx;
                Wt[((size_t)(n >> 4) * 64 + (k >> 3)) * 128
                   + (n & 15) * 8 + (k & 7)] = f2bf(t[lx * 65 + ly + i]);
            }
            __syncthreads();
        } else {                         // stats init (512 u64)
            stats[tid] = 0ull;
            stats[tid + 256] = 0ull;
        }
    }
}

// ---------------------------------------------------------------------------
// Unified MFMA GEMM (identical to r9): blocked operands, 1 KB wave loads.
__global__ __launch_bounds__(256) void k_mfma(
        const unsigned short* __restrict__ Ae, const unsigned short* __restrict__ Be,
        unsigned short* __restrict__ Ce,
        const unsigned short* __restrict__ Ad, const unsigned short* __restrict__ Bd,
        unsigned short* __restrict__ Cd)
{
    const int tid = threadIdx.x;
    const int w = tid >> 6, lane = tid & 63;
    const int quad = lane >> 4, l16 = lane & 15;
    const short* A; const short* Bt; unsigned short* C; int mb;
    if (blockIdx.y < 256) {
        A = (const short*)Ae; Bt = (const short*)Be; C = Ce; mb = blockIdx.y * 128;
    } else {
        A = (const short*)Ad; Bt = (const short*)Bd; C = Cd; mb = (blockIdx.y - 256) * 128;
    }
    const int m0 = mb + (w >> 1) * 64;
    const int n0 = blockIdx.x * 128 + (w & 1) * 64;

    const short* Ab = A  + (size_t)(m0 >> 4) * 64 * 128 + l16 * 8;
    const short* Bb = Bt + (size_t)(n0 >> 4) * 64 * 128 + l16 * 8;

    f32x4 acc[4][4] = {};
    for (int ks = 0; ks < K; ks += 32) {
        const int kc = (ks >> 3) + quad;      // this lane's k-chunk
        bf16x8 af[4], bg[4];
        #pragma unroll
        for (int i = 0; i < 4; i++)
            af[i] = *(const bf16x8*)(Ab + ((size_t)i * 64 + kc) * 128);
        #pragma unroll
        for (int j = 0; j < 4; j++)
            bg[j] = *(const bf16x8*)(Bb + ((size_t)j * 64 + kc) * 128);
        #pragma unroll
        for (int i = 0; i < 4; i++)
            #pragma unroll
            for (int j = 0; j < 4; j++)
                acc[i][j] = __builtin_amdgcn_mfma_f32_16x16x32_bf16(
                    af[i], bg[j], acc[i][j], 0, 0, 0);
    }
    #pragma unroll
    for (int i = 0; i < 4; i++)
        #pragma unroll
        for (int j = 0; j < 4; j++)
            #pragma unroll
            for (int r = 0; r < 4; r++) {
                int m = m0 + i * 16 + quad * 4 + r;
                int n = n0 + j * 16 + l16;
                C[(size_t)m * U + n] = f2bf(acc[i][j][r]);
            }
}

// ---------------------------------------------------------------------------
// Persistent scan v11: 256 blocks x 1024 threads, cooperative.
// = r9 EXACTLY (proven 352us k_scan; r12's paired-rcp reverted -- it
// regressed: trans and VALU share issue bandwidth) + CTX REDUCE FUSED into
// the epilogue (k_ctx launch eliminated):
//  * per-step myctx stores are st_agent (IC-visible fire-and-forget --
//    r0-proven mode; the expensive thing r3 removed was per-step remote
//    READS+drains, which stay removed: the reduce happens ONCE at the end).
//  * epilogue: vmcnt(0) per wave -> __syncthreads -> publish tag 65 into
//    slot 0 (last held 63, no ABA) -> wave-0 poll -> LBAR -> block (b,g)
//    reduces steps [g*8,g*8+8) with coalesced ld_agent loads.
__global__ __launch_bounds__(1024, 4) void k_scan(
        const unsigned short* __restrict__ enc_bf,
        const unsigned short* __restrict__ dec_bf,
        const unsigned short* en_bf,     // aliases pctx!
        const float* __restrict__ w_c,
        const float* __restrict__ v,
        const int* __restrict__ mask,
        unsigned long long* __restrict__ stats,  // [2][B][NB]
        float* pctx,                     // aliases en_bf! per-(b,g) slabs
        float* __restrict__ out)
{
    const int blk = blockIdx.x;
    const int b = blk & 31, g = blk >> 5;    // batch's 8 blocks share an XCD
    const int tid = threadIdx.x;
    const int w = tid >> 6, lane = tid & 63;
    const int u = lane * 8;

    __shared__ __align__(16) unsigned short s_enc[RPB * U];  // 128 KiB (by slot)
    __shared__ __align__(16) float s_p[RPB];  // unnormalized exp2(mu*L2E)/slot
    __shared__ float  s_cov[RPB];     // coverage per slot
    __shared__ short  s_rowid[RPB];   // slot -> batch row
    __shared__ unsigned long long s_bal[16];
    __shared__ float  s_wsum[16];
    __shared__ float  s_q[4][512];    // quarter ctx partials, 8 KiB
    __shared__ float  s_inv;

    const int* maskb = mask + b * TE;
    float* alphas = out + (size_t)B * TD * (DD + DE);
    float* covl   = alphas + (size_t)B * TD * TE;

    // lane-resident fragments: wcc = w_c*c (prescaled), vv, vsum (per-lane)
    float wcc[8], vv[8], vsuml;
    {
        float4 a0 = *(const float4*)&w_c[u];
        float4 a1 = *(const float4*)&w_c[u + 4];
        wcc[0]=a0.x*TANH_C; wcc[1]=a0.y*TANH_C; wcc[2]=a0.z*TANH_C; wcc[3]=a0.w*TANH_C;
        wcc[4]=a1.x*TANH_C; wcc[5]=a1.y*TANH_C; wcc[6]=a1.z*TANH_C; wcc[7]=a1.w*TANH_C;
        float4 b0 = *(const float4*)&v[u];
        float4 b1 = *(const float4*)&v[u + 4];
        vv[0]=b0.x; vv[1]=b0.y; vv[2]=b0.z; vv[3]=b0.w;
        vv[4]=b1.x; vv[5]=b1.y; vv[6]=b1.z; vv[7]=b1.w;
        vsuml = ((vv[0]+vv[1])+(vv[2]+vv[3])) + ((vv[4]+vv[5])+(vv[6]+vv[7]));
    }

    // ---- global active-row compaction (identical in all 8 blocks of b)
    int act = (maskb[tid] != 0);
    {
        unsigned long long bal = __ballot(act);
        if (lane == 0) s_bal[w] = bal;
        if (tid < RPB) { s_p[tid] = 0.f; s_cov[tid] = 0.f; s_rowid[tid] = 0; }
        __syncthreads();
    }
    int nact = 0, pre = 0;
    {
        #pragma unroll
        for (int ww = 0; ww < 16; ww++) {
            int c = __popcll(s_bal[ww]);
            if (ww < w) pre += c;
            nact += c;
        }
        pre += __popcll(s_bal[w] & ((1ull << lane) - 1));
        if (act && (pre & 7) == g) s_rowid[pre >> 3] = (short)tid;
    }
    const int Sblk = (nact + 7 - g) >> 3;    // assigned slots (<=128)

    // ---- zero alpha/covl for inactive rows of OWN slice, all steps (once)
    for (int t = tid; t < RPB * TD; t += 1024) {
        int rl = t & 127, s = t >> 7;
        if (maskb[g * RPB + rl] == 0) {
            size_t rowo = ((size_t)b * TD + s) * TE + g * RPB + rl;
            alphas[rowo] = 0.f;
            covl[rowo]   = 0.f;
        }
    }
    __syncthreads();   // s_rowid ready

    // ---- stage assigned rows' enc into LDS (slot-major), gather by rowid
    {
        const int slot = tid >> 3, part = tid & 7;   // 128 slots x 8 parts
        const uint4* src = (const uint4*)
            (enc_bf + ((size_t)b * TE + s_rowid[slot]) * U);
        uint4* dst = (uint4*)(s_enc + (size_t)slot * U);
        #pragma unroll
        for (int j = 0; j < 8; j++) dst[part + j * 8] = src[part + j * 8];
    }
    // ---- hoist assigned rows' en words (phase6 operands), by rowid
    //      en_bf is BLOCKED: word(rg,e2) = ((rg>>4)*64+(e2>>2))*64+(rg&15)*4+(e2&3)
    const int e2 = tid & 255, q4 = tid >> 8;   // 256 e-pairs x 4 quarters
    unsigned enreg[32];
    {
        const unsigned* enw = (const unsigned*)en_bf;
        #pragma unroll
        for (int r = 0; r < 32; r++) {
            int rg = b * TE + s_rowid[q4 * 32 + r];
            enreg[r] = enw[((size_t)(rg >> 4) * 64 + (e2 >> 2)) * 64
                           + (rg & 15) * 4 + (e2 & 3)];
        }
    }
    // private ctx slab: this (b,g)'s dead en_bf slice (64 steps x 512 f32)
    float* myctx = pctx + ((size_t)b * 1024 + g * RPB) * 256;

    __syncthreads();   // s_enc staged

    // pipelined dec fragment
    uint4 qd = *(const uint4*)(dec_bf + ((size_t)b * TD) * U + u);

    float inv_prev = 0.f;
    for (int s = 0; s < TD; s++) {
        // dfc = df * c (prescaled for the folded tanh argument)
        float dfc[8];
        unpack8(qd, dfc);
        #pragma unroll
        for (int j = 0; j < 8; j++) dfc[j] *= TANH_C;

        // ---- phase 1 (+fused phase 5 of step s-1) over own slots
        float local_esum = 0.f;
        for (int i = w; i < Sblk; i += 16) {
            float pold   = s_p[i];
            float covold = s_cov[i];
            float aprev  = pold * inv_prev;
            float cov    = covold + aprev;        // cov(s)
            if (s > 0 && lane == 0) {
                size_t rowo = ((size_t)b * TD + (s - 1)) * TE + s_rowid[i];
                alphas[rowo] = aprev;
                covl[rowo]   = fminf(covold, aprev);
            }
            uint4 q = *(const uint4*)(s_enc + (size_t)i * U + u);
            float e[8]; unpack8(q, e);
            float acc2 = 0.f;
            #pragma unroll
            for (int j = 0; j < 8; j++) {
                float arg = fmaf(cov, wcc[j], fmaf(e[j], TANH_C, dfc[j]));
                acc2 = fmaf(vv[j], RCPF(EXP2F(arg) + 1.0f), acc2);
            }
            // per-lane mu partial = vsum_l - 2*acc2_l (original cancellation)
            float part = fmaf(acc2, -2.0f, vsuml);
            part = wave_reduce_sum(part);         // = mu (wave-uniform)
            float pe = EXP2F(part * L2E);
            if (lane == 0) { s_p[i] = pe; s_cov[i] = cov; }
            local_esum += pe;
        }
        if (lane == 0) s_wsum[w] = local_esum;

        LBAR();   // B1: s_p/s_cov/s_wsum visible (LDS-only; no vmcnt drain)

        // ---- publish (sum_g | tag s+1): wave 0 lane 0
        unsigned long long* sl = stats + ((size_t)(s & 1) * B + b) * NB;
        if (w == 0) {
            float x = (lane < 16) ? s_wsum[lane] : 0.f;
            x += __shfl_xor(x, 8, 64);
            x += __shfl_xor(x, 4, 64);
            x += __shfl_xor(x, 2, 64);
            x += __shfl_xor(x, 1, 64);            // lane0: sum of 16
            if (lane == 0) {
                unsigned long long pv =
                    ((unsigned long long)__float_as_uint(x) << 32) |
                    (unsigned)(s + 1);
                st_agent64(&sl[g], pv);
            }
        }

        // ---- prefetch next dec fragment (hides under phase6 + poll)
        {
            int sn = (s + 1 < TD) ? s + 1 : s;
            qd = *(const uint4*)(dec_bf + (((size_t)b * TD + sn) * U + u));
        }

        // ---- phase 6: unnormalized ctx partial over own 32 slots -> s_q
        //      (s_p read as 8x float4: 4x fewer LDS instructions)
        {
            const float4* pb = (const float4*)&s_p[q4 * 32];
            float a0 = 0.f, a1 = 0.f;
            #pragma unroll
            for (int k = 0; k < 8; k++) {
                float4 pp = pb[k];
                a0 = fmaf(pp.x, bflo(enreg[4*k]),   a0);
                a1 = fmaf(pp.x, bfhi(enreg[4*k]),   a1);
                a0 = fmaf(pp.y, bflo(enreg[4*k+1]), a0);
                a1 = fmaf(pp.y, bfhi(enreg[4*k+1]), a1);
                a0 = fmaf(pp.z, bflo(enreg[4*k+2]), a0);
                a1 = fmaf(pp.z, bfhi(enreg[4*k+2]), a1);
                a0 = fmaf(pp.w, bflo(enreg[4*k+3]), a0);
                a1 = fmaf(pp.w, bfhi(enreg[4*k+3]), a1);
            }
            s_q[q4][2 * e2]     = a0;
            s_q[q4][2 * e2 + 1] = a1;
        }

        // ---- SINGLE-POLLER: wave 0 polls 8 tags -> inv -> s_inv
        if (w == 0) {
            unsigned long long pv = 0;
            for (;;) {
                if (lane < NB) pv = ld_agent64(&sl[lane]);
                unsigned long long okm =
                    __ballot(lane < NB ? ((unsigned)pv == (unsigned)(s + 1)) : 1);
                if (~okm == 0ull) break;
                __builtin_amdgcn_s_sleep(1);
            }
            float tg = (lane < NB) ? __uint_as_float((unsigned)(pv >> 32)) : 0.f;
            tg = wave_reduce_sum(tg);
            if (lane == 0) s_inv = RCPF(tg);
        }

        LBAR();   // B2: s_q + s_inv visible (LDS-only)

        inv_prev = s_inv;

        // ---- ctx(s) reduce + normalized st_agent store to private slab
        if (tid < 512) {
            float ts = s_q[0][tid] + s_q[1][tid] + s_q[2][tid] + s_q[3][tid];
            st_agent(&myctx[(size_t)s * 512 + tid], ts * inv_prev);
        }
    }

    // ---- epilogue A: flush alpha/covl for s = TD-1
    for (int i = w; i < Sblk; i += 16) {
        if (lane == 0) {
            float aprev = s_p[i] * inv_prev;
            size_t rowo = ((size_t)b * TD + (TD - 1)) * TE + s_rowid[i];
            alphas[rowo] = aprev;
            covl[rowo]   = fminf(s_cov[i], aprev);
        }
    }

    // ---- epilogue B: fused ctx final reduce (replaces k_ctx launch)
    // 1) drain this wave's pctx stores, barrier so the whole block is drained
    asm volatile("s_waitcnt vmcnt(0)" ::: "memory");
    __syncthreads();
    // 2) publish "slab complete" tag 65 into slot 0 (held 63 -> no ABA)
    {
        unsigned long long* sl = stats + ((size_t)(TD & 1) * B + b) * NB;
        if (w == 0 && lane == 0)
            st_agent64(&sl[g], (unsigned long long)(unsigned)(TD + 1));
        // 3) wave-0 poll: all 8 slabs of batch b complete
        if (w == 0) {
            unsigned long long pv = 0;
            for (;;) {
                if (lane < NB) pv = ld_agent64(&sl[lane]);
                unsigned long long okm =
                    __ballot(lane < NB ? ((unsigned)pv == (unsigned)(TD + 1)) : 1);
                if (~okm == 0ull) break;
                __builtin_amdgcn_s_sleep(1);
            }
        }
    }
    LBAR();
    // 4) block (b,g) reduces steps [g*8, g*8+8): 4096 outputs, coalesced
    for (int t = tid; t < 8 * 512; t += 1024) {
        int s2 = g * 8 + (t >> 9), e = t & 511;
        const float* pb2 = pctx + (size_t)b * 262144 + (size_t)s2 * 512 + e;
        float ts = 0.f;
        #pragma unroll
        for (int g2 = 0; g2 < NB; g2++) ts += ld_agent(pb2 + (size_t)g2 * 32768);
        out[((size_t)b * TD + s2) * (DD + DE) + DD + e] = ts;
    }
}

// ---------------------------------------------------------------------------
extern "C" void kernel_launch(void* const* d_in, const int* in_sizes, int n_in,
                              void* d_out, int out_size, void* d_ws, size_t ws_size,
                              hipStream_t stream) {
    const float* en_seq = (const float*)d_in[0];
    const float* de_seq = (const float*)d_in[1];
    const int*   mask   = (const int*)d_in[2];
    const float* W_h    = (const float*)d_in[3];
    const float* W_s    = (const float*)d_in[4];
    const float* w_c    = (const float*)d_in[5];
    const float* v      = (const float*)d_in[6];
    float* out = (float*)d_out;

    // workspace layout (~69 MiB, unchanged). en_bf doubles as the per-block
    // ctx-partial slab during k_scan (dead after the enreg hoist; per-batch
    // byte regions identical under the blocked layout).
    unsigned short* enc_bf = (unsigned short*)d_ws;        // B*TE*U  bf16 = 32 MiB
    unsigned short* en_bf  = enc_bf + (size_t)B * TE * U;  // B*TE*DE bf16 = 32 MiB (blocked)
    unsigned short* dec_bf = en_bf  + (size_t)B * TE * DE; // B*TD*U  bf16 = 2 MiB
    unsigned short* Wh_t   = dec_bf + (size_t)B * TD * U;  // 512*512 bf16 = 0.5 MiB (blocked)
    unsigned short* de_bf  = Wh_t   + (size_t)K * U;       // B*TD*DD bf16 = 2 MiB (blocked)
    unsigned short* Ws_t   = de_bf  + (size_t)B * TD * DD; // 0.5 MiB (blocked)
    unsigned long long* stats =
        (unsigned long long*)(Ws_t + (size_t)K * U);       // 512 u64
    float* pctx = (float*)en_bf;                           // alias

    k_prep<<<2048, 256, 0, stream>>>(en_seq, en_bf, de_seq, de_bf,
                                     (float4*)out, W_h, Wh_t, W_s, Ws_t, stats);
    k_mfma<<<dim3(4, 272), 256, 0, stream>>>(en_bf, Wh_t, enc_bf,
                                             de_bf, Ws_t, dec_bf);

    void* args[] = { (void*)&enc_bf, (void*)&dec_bf, (void*)&en_bf,
                     (void*)&w_c, (void*)&v, (void*)&mask,
                     (void*)&stats, (void*)&pctx, (void*)&out };
    hipLaunchCooperativeKernel((const void*)k_scan, dim3(256), dim3(1024),
                               args, 0, stream);
}